// Round 1
// 417.388 us; speedup vs baseline: 1.0585x; 1.0585x over previous
//
#include <hip/hip_runtime.h>
#include <math.h>

#define NB 36

// Inline exact-to-f32 atan2 (validated family: f64 internal, round==reference).
// v2: same error budget, fewer VALU slots than the Taylor-17 + v_div_f64 version:
//  - octant classification in f32 on exact pow2-scaled magnitudes (1-slot ops;
//    boundary +-1ulp reclassification harmless: both branches valid in overlap)
//  - q = num/den via v_rcp_f32 seed + 2 f64 Newton steps (~2^-51.8 rel)
//  - fdlibm e_atan.c 11-coeff minimax R(t): atan(q) = q*(1 - t*R(t)),
//    poly err ~2^-57 on |q| <= 7/16 (we use |q| <= 0.41422)
//  total rel err ~2^-50.7 (better than the ~2^-48.3 Taylor version that passed).
__device__ __forceinline__ float atan2f_cr(float gyf, float gxf) {
  // exact power-of-2 prescale: keeps den inside f32-normal range for rcp
  // (inputs are 2^-24-quantized so this is belt-and-braces, and it's 2 slots)
  float axf = fabsf(gxf) * 0x1p100f;
  float ayf = fabsf(gyf) * 0x1p100f;
  float mnf = fminf(axf, ayf);
  float mxf = fmaxf(axf, ayf);
  mxf = (mxf == 0.0f) ? 1.0f : mxf;        // gx=gy=0 guard -> q=0 -> a=0
  const bool hi   = mnf > 0.41421356f * mxf;
  const bool swp  = ayf > axf;

  double mn = (double)mnf, mx = (double)mxf;
  double s  = mn + mx;                     // <=2^-53 rel rounding
  double d  = mn - mx;
  double num = hi ? d : mn;
  double den = hi ? s : mx;

  // q = num/den to ~2^-51.8 rel: f32 rcp seed, two f64 Newton refinements
  double r = (double)__builtin_amdgcn_rcpf((float)den);
  r = fma(fma(-den, r, 1.0), r, r);        // err ~2^-44
  r = fma(fma(-den, r, 1.0), r, r);        // err ~2^-52.7
  double q = num * r;
  double t = q * q;

  // fdlibm aT[] minimax, Horner in t (identical polynomial to even/odd split)
  double R =      1.62858201153657823623e-02;
  R = fma(R, t, -3.65315727442169155270e-02);
  R = fma(R, t,  4.97687799461593236017e-02);
  R = fma(R, t, -5.83357013379057348645e-02);
  R = fma(R, t,  6.66107313738753120669e-02);
  R = fma(R, t, -7.69187620504482999495e-02);
  R = fma(R, t,  9.09088713343650656196e-02);
  R = fma(R, t, -1.11111104054623557880e-01);
  R = fma(R, t,  1.42857142725034663711e-01);
  R = fma(R, t, -1.99999999998764832476e-01);
  R = fma(R, t,  3.33333333333329318027e-01);
  double h = t * R;
  double a = fma(q, -h, q);                // q*(1 - t*R), single rounding

  // baseline's exact 3-step octant fixup sequence (bit-identical roundings)
  a = hi            ? (0.7853981633974483 + a) : a;
  a = swp           ? (1.5707963267948966 - a) : a;
  a = (gxf < 0.0f)  ? (3.141592653589793  - a) : a;   // a >= 0 here
  return copysignf((float)a, gyf);
}

// Exact f32 per-pixel pipeline: contract(off), reference association order,
// CR atan2, per-lane hist += in pixel order.  o_big's f32 divide by TPI_F is
// replaced by one f64 multiply with the CR reciprocal of the f32 constant
// (compile-time folded).  Provably bit-identical to f32 division: no exact
// midpoints exist (odd*13176795 > 2^24), and the 24b/24b quotient gap to any
// f32 midpoint (>= ~2^-49.7) exceeds the 2^-52 f64 error.
#define PX(L, R, UP, DN, G) do {                                    \
    float gx_ = 0.5f * ((L) - (R));                                 \
    float gy_ = 0.5f * ((UP) - (DN));                               \
    float m2_ = ((gx_ * gx_) + (gy_ * gy_)) + 1e-10f;               \
    float mag_ = sqrtf(m2_) * (G);                                  \
    float ori_ = atan2f_cr(gy_, gx_);                               \
    float ob_ = (float)((double)(36.0f * (ori_ + PI_F)) * INV_TPI_D); \
    float fo_ = floorf(ob_);                                        \
    float wo1_ = ob_ - fo_;                                         \
    int b0_ = (int)fo_;                                             \
    if (b0_ >= NB) b0_ -= NB;                                       \
    h[b0_] += (1.0f - wo1_) * mag_;                                 \
  } while (0)

#define QUAD(cq, uq, dq, gq, LV, RV) do {                           \
    PX(LV,   cq.y, uq.x, dq.x, gq.x);                               \
    PX(cq.x, cq.z, uq.y, dq.y, gq.y);                               \
    PX(cq.y, cq.w, uq.z, dq.z, gq.z);                               \
    PX(cq.z, RV,   uq.w, dq.w, gq.w);                               \
  } while (0)

#define UP1(v) __shfl_up((v), 1, 32)
#define DN1(v) __shfl_down((v), 1, 32)

// One WAVE per 32x32 patch. lane = row + 32*half; lane owns 16 contiguous
// pixels (row, cols half*16..+15) -> all loads hit the wave's own 4KB patch;
// vertical stencil = shfl +-1 width 32 (clamp == replicate pad), half
// boundary = one shfl_xor(32). Per-LANE 36-bin LDS hist (stride 37: bank
// (5*lane+b)%32 -> <=2-way, free), accumulated in each lane's ascending
// pixel order; then per-bin reduction over the 64 lane-hists in pixel-RUN
// order (the only deviation from the reference's fully-sequential sum:
// run-partial regrouping, ~ulp noise, argmax-safe w.h.p.). No block syncs:
// all LDS traffic is intra-wave (DS ops in-order per wave).
__global__ __launch_bounds__(256, 4) void orient_kernel(
    const float* __restrict__ x,
    const float* __restrict__ gk,
    float* __restrict__ out)
{
#pragma clang fp contract(off)
  __shared__ float hist[256 * 37];   // 37888 B -> 4 blocks/CU

  const int t    = threadIdx.x;
  const int lane = t & 63;
  const int row  = lane & 31;
  const int half = lane >> 5;
  const int p    = (blockIdx.x * 256 + t) >> 6;   // global wave id == patch

  const float PI_F  = 3.14159265358979323846f;   // 0x40490FDB
  const float TPI_F = 6.28318530717958647692f;   // 0x40C90FDB
  const double INV_TPI_D = 1.0 / (double)6.28318530717958647692f; // CR recip of f32 const

  float* __restrict__ h = &hist[t * 37];
  #pragma unroll
  for (int b = 0; b < NB; ++b) h[b] = 0.0f;

  const float4* __restrict__ xv =
      (const float4*)(x + (size_t)p * 1024 + (row * 32 + half * 16));
  const float4* __restrict__ gv = (const float4*)(gk + (row * 32 + half * 16));
  float4 c0 = xv[0], c1 = xv[1], c2 = xv[2], c3 = xv[3];
  float4 g0 = gv[0], g1 = gv[1], g2 = gv[2], g3 = gv[3];

  float4 u0, u1, u2, u3, d0, d1, d2, d3;
  u0.x=UP1(c0.x); u0.y=UP1(c0.y); u0.z=UP1(c0.z); u0.w=UP1(c0.w);
  u1.x=UP1(c1.x); u1.y=UP1(c1.y); u1.z=UP1(c1.z); u1.w=UP1(c1.w);
  u2.x=UP1(c2.x); u2.y=UP1(c2.y); u2.z=UP1(c2.z); u2.w=UP1(c2.w);
  u3.x=UP1(c3.x); u3.y=UP1(c3.y); u3.z=UP1(c3.z); u3.w=UP1(c3.w);
  d0.x=DN1(c0.x); d0.y=DN1(c0.y); d0.z=DN1(c0.z); d0.w=DN1(c0.w);
  d1.x=DN1(c1.x); d1.y=DN1(c1.y); d1.z=DN1(c1.z); d1.w=DN1(c1.w);
  d2.x=DN1(c2.x); d2.y=DN1(c2.y); d2.z=DN1(c2.z); d2.w=DN1(c2.w);
  d3.x=DN1(c3.x); d3.y=DN1(c3.y); d3.z=DN1(c3.z); d3.w=DN1(c3.w);

  float send = half ? c0.x : c3.w;
  float recv = __shfl_xor(send, 32, 64);
  float LB = half ? recv : c0.x;    // left neighbor of this chunk's col 0
  float RB = half ? c3.w : recv;    // right neighbor of this chunk's col 15

  QUAD(c0, u0, d0, g0, LB,   c1.x);
  QUAD(c1, u1, d1, g1, c0.w, c2.x);
  QUAD(c2, u2, d2, g2, c1.w, c3.x);
  QUAD(c3, u3, d3, g3, c2.w, RB);

  __builtin_amdgcn_wave_barrier();   // keep phase order; DS in-order per wave

  // per-bin reduction over lane-hists in pixel-run order:
  // run k covers pixels [k*16, k*16+16) -> owning lane = (k>>1) + 32*(k&1)
  const float* __restrict__ hw = &hist[(t >> 6) * 2368];
  const int bb = (lane < NB) ? lane : NB - 1;     // clamp; masked later
  float s = 0.0f;
  #pragma unroll
  for (int k = 0; k < 64; ++k) {
    const int l = (k >> 1) + ((k & 1) << 5);
    s += hw[l * 37 + bb];
  }

  // zero-padded [0.33,0.34,0.33] smooth + 64-lane first-index argmax
  float ll = __shfl(s, lane - 1);
  float rr = __shfl(s, lane + 1);
  float v; int idx;
  if (lane < NB) {
    float sl = (lane > 0)      ? ll : 0.0f;
    float sr = (lane < NB - 1) ? rr : 0.0f;
    v = (0.33f * sl + 0.34f * s) + 0.33f * sr;    // ref association
    idx = lane;
  } else {
    v = -INFINITY; idx = 1 << 20;
  }
  #pragma unroll
  for (int off = 32; off > 0; off >>= 1) {
    float v2 = __shfl_xor(v, off, 64);
    int   i2 = __shfl_xor(idx, off, 64);
    if (v2 > v || (v2 == v && i2 < idx)) { v = v2; idx = i2; }
  }
  if (lane == 0) {
    out[p] = -((TPI_F * (float)idx) / 36.0f - PI_F);
  }
}

extern "C" void kernel_launch(void* const* d_in, const int* in_sizes, int n_in,
                              void* d_out, int out_size, void* d_ws, size_t ws_size,
                              hipStream_t stream) {
  const float* x  = (const float*)d_in[0];
  const float* gk = (const float*)d_in[1];
  float* out = (float*)d_out;
  const int B = in_sizes[0] / 1024;        // 65536 patches
  orient_kernel<<<B / 4, 256, 0, stream>>>(x, gk, out);
}

// Round 2
// 399.599 us; speedup vs baseline: 1.1056x; 1.0445x over previous
//
#include <hip/hip_runtime.h>
#include <math.h>

#define NB 36

// Init-only f64 atan for u in [0,1]: octant reduce + fdlibm 11-coeff minimax
// (coefficient list identical to the round-1 validated kernel). err ~2^-52.
// Used once per block to build atab[k] = atan(k/8); the f64 division here is
// compiler-CR (full sequence) -- cost irrelevant at init.
__device__ __forceinline__ double atan_ref64(double u) {
  bool hi = u > 0.41421356237309503;
  double q = hi ? (u - 1.0) / (u + 1.0) : u;
  double t = q * q;
  double R =      1.62858201153657823623e-02;
  R = fma(R, t, -3.65315727442169155270e-02);
  R = fma(R, t,  4.97687799461593236017e-02);
  R = fma(R, t, -5.83357013379057348645e-02);
  R = fma(R, t,  6.66107313738753120669e-02);
  R = fma(R, t, -7.69187620504482999495e-02);
  R = fma(R, t,  9.09088713343650656196e-02);
  R = fma(R, t, -1.11111104054623557880e-01);
  R = fma(R, t,  1.42857142725034663711e-01);
  R = fma(R, t, -1.99999999998764832476e-01);
  R = fma(R, t,  3.33333333333329318027e-01);
  double h = t * R;
  double a = fma(-h, q, q);
  return hi ? (0.7853981633974483 + a) : a;
}

// Fast exact-enough atan2 (total ori err ~2^-45.8 rel / ~2^-49.8 rad abs):
//  - c = round(8*mn/mx)/8 via HW rcp; atan(mn/mx) = atab[8c] + atan(q),
//    q = (mn - c*mx)/(mx + c*mn), |q| <= 1/16.  num/den are EXACT f64 fmas
//    (scaled-integer args: 8i-kj, 8j+ki fit 28 bits; inputs are 2^-24 grid).
//  - q via rcp_f32 seed + ONE f64 Newton (2^-23 -> 2^-45.9).
//  - poly: Taylor through t^5/11 (remainder 2^-51.7 at t<=2^-8), f64 head
//    (1/3, 1/5) + f32 tail (1/7, 1/9, 1/11; contributes t^3*2^-25 ~ 2^-49).
//  - fixup chain (pi/2-swap, pi-neg) identical roundings to validated kernel.
// Bin-flip expectation at this budget ~1e-6 over all 67M pixels.
__device__ __forceinline__ float atan2f_fast(float gyf, float gxf,
                                             const double* __restrict__ atab) {
  float axf = fabsf(gxf);
  float ayf = fabsf(gyf);
  float mnf = fminf(axf, ayf);
  float mxf = fmaxf(axf, ayf);
  float mxg = (mxf == 0.0f) ? 1.0f : mxf;   // gx=gy=0 -> q=0, a=0
  const bool swp = ayf > axf;

  float r0 = __builtin_amdgcn_rcpf(mxg);    // seed for the ratio only
  float c8 = rintf(mnf * (8.0f * r0));      // k in 0..8 (mn<=mx -> <=8)
  int   k  = (int)c8;
  float cf = c8 * 0.125f;

  double mn = (double)mnf, mx = (double)mxg, cd = (double)cf;
  double num = fma(-cd, mx, mn);            // exact
  double den = fma( cd, mn, mx);            // exact, in [mx, 2*mx)

  float denf = fmaf(cf, mnf, mxg);
  double rd = (double)__builtin_amdgcn_rcpf(denf);
  rd = fma(fma(-den, rd, 1.0), rd, rd);     // one f64 Newton: ~2^-45.9
  double q = num * rd;                      // |q| <= 1/16
  double t = q * q;                         // t <= 2^-8

  float tf = (float)t;
  float V = fmaf(-tf, fmaf(-tf, 1.0f/11.0f, 1.0f/9.0f), 1.0f/7.0f);
  double S = fma(-t, (double)V, 0.2);       // 1/5 - t*V
  double R = fma(-t, S, 1.0/3.0);           // 1/3 - t*S
  double h = t * R;
  double a = fma(-h, q, q);                 // q*(1 - t*R) = atan(q)

  a = atab[k] + a;                          // atan(mn/mx) in [0, pi/4]
  a = swp         ? (1.5707963267948966 - a) : a;
  a = (gxf < 0.0f)? (3.141592653589793  - a) : a;
  return copysignf((float)a, gyf);
}

// Per-pixel pipeline.  b0/wo1 are exact (CR atan2-chain + Markstein CR f32
// division for ob); mag/weight use fma folding + raw v_sqrt (<=1ulp) -- this
// perturbs histogram WEIGHTS only at the same ulp level as the already-
// accepted lane-hist regrouping noise (argmax-safe w.h.p.).
#define PX(L, R, UP, DN, G) do {                                    \
    float gx_ = 0.5f * ((L) - (R));                                 \
    float gy_ = 0.5f * ((UP) - (DN));                               \
    float m2_ = fmaf(gy_, gy_, fmaf(gx_, gx_, 1e-10f));             \
    float mag_ = __builtin_amdgcn_sqrtf(m2_) * (G);                 \
    float ori_ = atan2f_fast(gy_, gx_, atab);                       \
    float s1_ = ori_ + PI_F;                                        \
    float d2_ = 36.0f * s1_;                                        \
    float q0_ = d2_ * C_INV_TPI;      /* Markstein CR f32 division */ \
    float rm_ = fmaf(-TPI_F, q0_, d2_);                             \
    float ob_ = fmaf(rm_, C_INV_TPI, q0_);                          \
    float fo_ = floorf(ob_);                                        \
    float wo1_ = ob_ - fo_;                                         \
    int b0_ = (int)fo_;                                             \
    if (b0_ >= NB) b0_ -= NB;                                       \
    h[b0_] += fmaf(-wo1_, mag_, mag_);                              \
  } while (0)

#define QUAD(cq, uq, dq, gq, LV, RV) do {                           \
    PX(LV,   cq.y, uq.x, dq.x, gq.x);                               \
    PX(cq.x, cq.z, uq.y, dq.y, gq.y);                               \
    PX(cq.y, cq.w, uq.z, dq.z, gq.z);                               \
    PX(cq.z, RV,   uq.w, dq.w, gq.w);                               \
  } while (0)

#define UP1(v) __shfl_up((v), 1, 32)
#define DN1(v) __shfl_down((v), 1, 32)

// One WAVE per 32x32 patch. lane = row + 32*half; lane owns 16 contiguous
// pixels (row, cols half*16..+15); vertical stencil = shfl +-1 width 32
// (clamp == replicate pad), half boundary = one shfl_xor(32). Per-LANE
// 36-bin LDS hist (stride 37), accumulated in each lane's ascending pixel
// order; per-bin reduction over lane-hists in pixel-run order (validated
// regrouping). One __syncthreads() publishes the per-block atan table; all
// other LDS traffic is intra-wave.
__global__ __launch_bounds__(256, 4) void orient_kernel(
    const float* __restrict__ x,
    const float* __restrict__ gk,
    float* __restrict__ out)
{
#pragma clang fp contract(off)
  __shared__ float hist[256 * 37];   // 37888 B
  __shared__ double atab[9];         // +72 B -> 37960 B, still 4 blocks/CU

  const int t    = threadIdx.x;
  const int lane = t & 63;
  const int row  = lane & 31;
  const int half = lane >> 5;
  const int p    = (blockIdx.x * 256 + t) >> 6;   // global wave id == patch

  const float PI_F  = 3.14159265358979323846f;   // 0x40490FDB
  const float TPI_F = 6.28318530717958647692f;   // 0x40C90FDB
  const float C_INV_TPI = (float)(1.0 / (double)6.28318530717958647692f);

  if (t < 9) atab[t] = atan_ref64((double)t * 0.125);

  float* __restrict__ h = &hist[t * 37];
  #pragma unroll
  for (int b = 0; b < NB; ++b) h[b] = 0.0f;

  __syncthreads();                   // publish atab to all 4 waves

  const float4* __restrict__ xv =
      (const float4*)(x + (size_t)p * 1024 + (row * 32 + half * 16));
  const float4* __restrict__ gv = (const float4*)(gk + (row * 32 + half * 16));
  float4 c0 = xv[0], c1 = xv[1], c2 = xv[2], c3 = xv[3];
  float4 g0 = gv[0], g1 = gv[1], g2 = gv[2], g3 = gv[3];

  float4 u0, u1, u2, u3, d0, d1, d2, d3;
  u0.x=UP1(c0.x); u0.y=UP1(c0.y); u0.z=UP1(c0.z); u0.w=UP1(c0.w);
  u1.x=UP1(c1.x); u1.y=UP1(c1.y); u1.z=UP1(c1.z); u1.w=UP1(c1.w);
  u2.x=UP1(c2.x); u2.y=UP1(c2.y); u2.z=UP1(c2.z); u2.w=UP1(c2.w);
  u3.x=UP1(c3.x); u3.y=UP1(c3.y); u3.z=UP1(c3.z); u3.w=UP1(c3.w);
  d0.x=DN1(c0.x); d0.y=DN1(c0.y); d0.z=DN1(c0.z); d0.w=DN1(c0.w);
  d1.x=DN1(c1.x); d1.y=DN1(c1.y); d1.z=DN1(c1.z); d1.w=DN1(c1.w);
  d2.x=DN1(c2.x); d2.y=DN1(c2.y); d2.z=DN1(c2.z); d2.w=DN1(c2.w);
  d3.x=DN1(c3.x); d3.y=DN1(c3.y); d3.z=DN1(c3.z); d3.w=DN1(c3.w);

  float send = half ? c0.x : c3.w;
  float recv = __shfl_xor(send, 32, 64);
  float LB = half ? recv : c0.x;    // left neighbor of this chunk's col 0
  float RB = half ? c3.w : recv;    // right neighbor of this chunk's col 15

  QUAD(c0, u0, d0, g0, LB,   c1.x);
  QUAD(c1, u1, d1, g1, c0.w, c2.x);
  QUAD(c2, u2, d2, g2, c1.w, c3.x);
  QUAD(c3, u3, d3, g3, c2.w, RB);

  __builtin_amdgcn_wave_barrier();   // keep phase order; DS in-order per wave

  // per-bin reduction over lane-hists in pixel-run order:
  // run k covers pixels [k*16, k*16+16) -> owning lane = (k>>1) + 32*(k&1)
  const float* __restrict__ hw = &hist[(t >> 6) * 2368];
  const int bb = (lane < NB) ? lane : NB - 1;     // clamp; masked later
  float s = 0.0f;
  #pragma unroll
  for (int k = 0; k < 64; ++k) {
    const int l = (k >> 1) + ((k & 1) << 5);
    s += hw[l * 37 + bb];
  }

  // zero-padded [0.33,0.34,0.33] smooth + 64-lane first-index argmax
  float ll = __shfl(s, lane - 1);
  float rr = __shfl(s, lane + 1);
  float v; int idx;
  if (lane < NB) {
    float sl = (lane > 0)      ? ll : 0.0f;
    float sr = (lane < NB - 1) ? rr : 0.0f;
    v = (0.33f * sl + 0.34f * s) + 0.33f * sr;    // ref association
    idx = lane;
  } else {
    v = -INFINITY; idx = 1 << 20;
  }
  #pragma unroll
  for (int off = 32; off > 0; off >>= 1) {
    float v2 = __shfl_xor(v, off, 64);
    int   i2 = __shfl_xor(idx, off, 64);
    if (v2 > v || (v2 == v && i2 < idx)) { v = v2; idx = i2; }
  }
  if (lane == 0) {
    out[p] = -((TPI_F * (float)idx) / 36.0f - PI_F);
  }
}

extern "C" void kernel_launch(void* const* d_in, const int* in_sizes, int n_in,
                              void* d_out, int out_size, void* d_ws, size_t ws_size,
                              hipStream_t stream) {
  const float* x  = (const float*)d_in[0];
  const float* gk = (const float*)d_in[1];
  float* out = (float*)d_out;
  const int B = in_sizes[0] / 1024;        // 65536 patches
  orient_kernel<<<B / 4, 256, 0, stream>>>(x, gk, out);
}